// Round 8
// baseline (309.137 us; speedup 1.0000x reference)
//
#include <hip/hip_runtime.h>

// VecInt: scaling-and-squaring integration, vel [2,128,128,128,3] fp32.
// v = vel/2^7; 7x: v = v + warp(v, v)  (border-clipped trilinear).
//
// Round-8: identical to round-7 except the one-line batch-decode fix in
// vecint_mid_lds (b = bid >> 10, not >> 11 — tile coords use 10 bits; the
// bug left batch 1 unintegrated).  Steps 2-6: LDS-staged gather (16x8x16
// tile + 2-halo = 38.4KB, coalesced staging, rare global fallback).

#define NVOX_PER_B (1 << 21)          // 128^3

typedef _Float16 h16;
typedef __attribute__((ext_vector_type(4))) _Float16 h16x4;   // 8 bytes

// tile geometry for the LDS mid kernel
#define TX 16
#define TY 8
#define TZ 16
#define LX (TX + 4)                  // 20
#define LY (TY + 4)                  // 12
#define LZ (TZ + 4)                  // 20
#define LDS_N (LX * LY * LZ)         // 4800 voxels * 8B = 38400 B

// ---- shared address/weight computation --------------------------------
__device__ __forceinline__ void tri_setup_idx(
    int x, int y, int z, float fx, float fy, float fz,
    int& x0, int& x1, int& y0, int& y1, int& z0, int& z1, float* w)
{
    float lx = fminf(fmaxf((float)x + fx, 0.0f), 127.0f);
    float ly = fminf(fmaxf((float)y + fy, 0.0f), 127.0f);
    float lz = fminf(fmaxf((float)z + fz, 0.0f), 127.0f);

    float flx = floorf(lx), fly = floorf(ly), flz = floorf(lz);
    float wx1 = lx - flx, wy1 = ly - fly, wz1 = lz - flz;
    float wx0 = 1.0f - wx1, wy0 = 1.0f - wy1, wz0 = 1.0f - wz1;

    x0 = (int)flx; y0 = (int)fly; z0 = (int)flz;
    x1 = min(x0 + 1, 127);
    y1 = min(y0 + 1, 127);
    z1 = min(z0 + 1, 127);

    w[0] = wx0 * wy0 * wz0;  w[1] = wx0 * wy0 * wz1;
    w[2] = wx0 * wy1 * wz0;  w[3] = wx0 * wy1 * wz1;
    w[4] = wx1 * wy0 * wz0;  w[5] = wx1 * wy0 * wz1;
    w[6] = wx1 * wy1 * wz0;  w[7] = wx1 * wy1 * wz1;
}

// ---- step 1: f32 packed vel -> fp16x4 field (fuses the /128 scale) -----
__global__ __launch_bounds__(256) void vecint_first(
    const float* __restrict__ vin, h16x4* __restrict__ vout,
    float scale, int nvox)
{
    int idx = blockIdx.x * blockDim.x + threadIdx.x;
    if (idx >= nvox) return;

    int z = idx & 127;
    int y = (idx >> 7) & 127;
    int x = (idx >> 14) & 127;
    int b = idx >> 21;

    int base = idx * 3;
    float fx = vin[base + 0] * scale;
    float fy = vin[base + 1] * scale;
    float fz = vin[base + 2] * scale;

    int x0, x1, y0, y1, z0, z1; float w[8];
    tri_setup_idx(x, y, z, fx, fy, fz, x0, x1, y0, y1, z0, z1, w);

    int off[8];
    off[0] = (x0 << 14) + (y0 << 7) + z0;  off[1] = (x0 << 14) + (y0 << 7) + z1;
    off[2] = (x0 << 14) + (y1 << 7) + z0;  off[3] = (x0 << 14) + (y1 << 7) + z1;
    off[4] = (x1 << 14) + (y0 << 7) + z0;  off[5] = (x1 << 14) + (y0 << 7) + z1;
    off[6] = (x1 << 14) + (y1 << 7) + z0;  off[7] = (x1 << 14) + (y1 << 7) + z1;

    const float* vb = vin + (size_t)b * (NVOX_PER_B * 3);
    float ox = 0.0f, oy = 0.0f, oz = 0.0f;
#pragma unroll
    for (int c = 0; c < 8; ++c) {
        const float* p = vb + (size_t)off[c] * 3;
        ox += w[c] * p[0]; oy += w[c] * p[1]; oz += w[c] * p[2];
    }

    h16x4 o;
    o.x = (h16)(fx + scale * ox);
    o.y = (h16)(fy + scale * oy);
    o.z = (h16)(fz + scale * oz);
    o.w = (h16)0.0f;
    vout[idx] = o;
}

// ---- steps 2..6: LDS-staged fp16x4 -> fp16x4 ---------------------------
__global__ __launch_bounds__(256) void vecint_mid_lds(
    const h16x4* __restrict__ vin, h16x4* __restrict__ vout)
{
    __shared__ h16x4 tile[LDS_N];

    int bid = blockIdx.x;
    int tz = bid & 7;            // 8 z-tiles      (bits 0-2)
    int ty = (bid >> 3) & 15;    // 16 y-tiles     (bits 3-6)
    int tx = (bid >> 7) & 7;     // 8 x-tiles      (bits 7-9)
    int b  = bid >> 10;          // 2 batches      (bit 10)  [R8 FIX]
    int X0 = tx * TX, Y0 = ty * TY, Z0 = tz * TZ;

    const h16x4* vb = vin + ((size_t)b << 21);

    // stage tile + halo, edge-clamped (consistent with border-clip gather)
    for (int s = (int)threadIdx.x; s < LDS_N; s += 256) {
        int lz = s % LZ;
        int r  = s / LZ;
        int ly = r % LY;
        int lx = r / LY;
        int gx = min(max(X0 - 2 + lx, 0), 127);
        int gy = min(max(Y0 - 2 + ly, 0), 127);
        int gz = min(max(Z0 - 2 + lz, 0), 127);
        tile[s] = vb[(gx << 14) + (gy << 7) + gz];
    }
    __syncthreads();

#pragma unroll
    for (int j = 0; j < 8; ++j) {
        int wv = (int)threadIdx.x + 256 * j;
        int vz = wv & 15;
        int vy = (wv >> 4) & 7;
        int vx = wv >> 7;              // 0..15
        int x = X0 + vx, y = Y0 + vy, z = Z0 + vz;

        h16x4 f = tile[((vx + 2) * LY + (vy + 2)) * LZ + (vz + 2)];
        float fx = (float)f.x, fy = (float)f.y, fz = (float)f.z;

        int x0, x1, y0, y1, z0, z1; float w[8];
        tri_setup_idx(x, y, z, fx, fy, fz, x0, x1, y0, y1, z0, z1, w);

        int lx0 = x0 - X0 + 2, lx1 = x1 - X0 + 2;
        int ly0 = y0 - Y0 + 2, ly1 = y1 - Y0 + 2;
        int lz0 = z0 - Z0 + 2, lz1 = z1 - Z0 + 2;

        float ox = 0.0f, oy = 0.0f, oz = 0.0f;
        bool in_tile = (lx0 >= 0) & (lx1 < LX) & (ly0 >= 0) & (ly1 < LY)
                     & (lz0 >= 0) & (lz1 < LZ);
        if (in_tile) {
            int r00 = (lx0 * LY + ly0) * LZ, r01 = (lx0 * LY + ly1) * LZ;
            int r10 = (lx1 * LY + ly0) * LZ, r11 = (lx1 * LY + ly1) * LZ;
            h16x4 c0 = tile[r00 + lz0], c1 = tile[r00 + lz1];
            h16x4 c2 = tile[r01 + lz0], c3 = tile[r01 + lz1];
            h16x4 c4 = tile[r10 + lz0], c5 = tile[r10 + lz1];
            h16x4 c6 = tile[r11 + lz0], c7 = tile[r11 + lz1];
            ox = w[0]*(float)c0.x + w[1]*(float)c1.x + w[2]*(float)c2.x + w[3]*(float)c3.x
               + w[4]*(float)c4.x + w[5]*(float)c5.x + w[6]*(float)c6.x + w[7]*(float)c7.x;
            oy = w[0]*(float)c0.y + w[1]*(float)c1.y + w[2]*(float)c2.y + w[3]*(float)c3.y
               + w[4]*(float)c4.y + w[5]*(float)c5.y + w[6]*(float)c6.y + w[7]*(float)c7.y;
            oz = w[0]*(float)c0.z + w[1]*(float)c1.z + w[2]*(float)c2.z + w[3]*(float)c3.z
               + w[4]*(float)c4.z + w[5]*(float)c5.z + w[6]*(float)c6.z + w[7]*(float)c7.z;
        } else {
            int off[8];
            off[0] = (x0 << 14) + (y0 << 7) + z0;  off[1] = (x0 << 14) + (y0 << 7) + z1;
            off[2] = (x0 << 14) + (y1 << 7) + z0;  off[3] = (x0 << 14) + (y1 << 7) + z1;
            off[4] = (x1 << 14) + (y0 << 7) + z0;  off[5] = (x1 << 14) + (y0 << 7) + z1;
            off[6] = (x1 << 14) + (y1 << 7) + z0;  off[7] = (x1 << 14) + (y1 << 7) + z1;
#pragma unroll
            for (int c = 0; c < 8; ++c) {
                h16x4 cv = vb[off[c]];
                ox += w[c] * (float)cv.x;
                oy += w[c] * (float)cv.y;
                oz += w[c] * (float)cv.z;
            }
        }

        h16x4 o;
        o.x = (h16)(fx + ox);
        o.y = (h16)(fy + oy);
        o.z = (h16)(fz + oz);
        o.w = (h16)0.0f;
        vout[(b << 21) + (x << 14) + (y << 7) + z] = o;
    }
}

// ---- step 7: fp16x4 -> f32 packed --------------------------------------
__global__ __launch_bounds__(256) void vecint_last(
    const h16x4* __restrict__ vin, float* __restrict__ vout, int nvox)
{
    int idx = blockIdx.x * blockDim.x + threadIdx.x;
    if (idx >= nvox) return;

    int z = idx & 127;
    int y = (idx >> 7) & 127;
    int x = (idx >> 14) & 127;
    int b = idx >> 21;

    h16x4 f = vin[idx];
    float fx = (float)f.x, fy = (float)f.y, fz = (float)f.z;

    int x0, x1, y0, y1, z0, z1; float w[8];
    tri_setup_idx(x, y, z, fx, fy, fz, x0, x1, y0, y1, z0, z1, w);

    int off[8];
    off[0] = (x0 << 14) + (y0 << 7) + z0;  off[1] = (x0 << 14) + (y0 << 7) + z1;
    off[2] = (x0 << 14) + (y1 << 7) + z0;  off[3] = (x0 << 14) + (y1 << 7) + z1;
    off[4] = (x1 << 14) + (y0 << 7) + z0;  off[5] = (x1 << 14) + (y0 << 7) + z1;
    off[6] = (x1 << 14) + (y1 << 7) + z0;  off[7] = (x1 << 14) + (y1 << 7) + z1;

    const h16x4* vb = vin + ((size_t)b << 21);
    float ox = 0.0f, oy = 0.0f, oz = 0.0f;
#pragma unroll
    for (int c = 0; c < 8; ++c) {
        h16x4 cv = vb[off[c]];
        ox += w[c] * (float)cv.x;
        oy += w[c] * (float)cv.y;
        oz += w[c] * (float)cv.z;
    }

    int base = idx * 3;
    vout[base + 0] = fx + ox;
    vout[base + 1] = fy + oy;
    vout[base + 2] = fz + oz;
}

extern "C" void kernel_launch(void* const* d_in, const int* in_sizes, int n_in,
                              void* d_out, int out_size, void* d_ws, size_t ws_size,
                              hipStream_t stream) {
    const float* vel = (const float*)d_in[0];
    float* out = (float*)d_out;

    int nvox = in_sizes[0] / 3;            // 4,194,304 voxels (2 batches)
    int blocks = (nvox + 255) / 256;       // 16384
    int tblocks = 2 * 8 * 16 * 8;          // 2048 tile-blocks for LDS mids
    float s0 = 1.0f / 128.0f;              // 1 / 2^INT_STEPS

    // D = fp16 field in the first 33.5 MB of d_out; W = fp16 field in d_ws.
    h16x4* D = (h16x4*)d_out;
    h16x4* W = (h16x4*)d_ws;

    vecint_first  <<<blocks,  256, 0, stream>>>(vel, D, s0, nvox);  // 1: vel->D
    vecint_mid_lds<<<tblocks, 256, 0, stream>>>(D, W);              // 2: D->W
    vecint_mid_lds<<<tblocks, 256, 0, stream>>>(W, D);              // 3: W->D
    vecint_mid_lds<<<tblocks, 256, 0, stream>>>(D, W);              // 4: D->W
    vecint_mid_lds<<<tblocks, 256, 0, stream>>>(W, D);              // 5: W->D
    vecint_mid_lds<<<tblocks, 256, 0, stream>>>(D, W);              // 6: D->W
    vecint_last   <<<blocks,  256, 0, stream>>>(W, out, nvox);      // 7: W->out
}